// Round 7
// baseline (359.761 us; speedup 1.0000x reference)
//
#include <hip/hip_runtime.h>
#include <stdint.h>
#include <math.h>

#define NPAD 4224   // padded N for the fused qkv+ab GEMM (4128 -> 33*128)

typedef float  f32x4_t __attribute__((ext_vector_type(4)));
typedef __bf16 bfx8_t  __attribute__((ext_vector_type(8)));
typedef __bf16 bfx4_t  __attribute__((ext_vector_type(4)));

#define F4(p)  (*reinterpret_cast<const float4*>(p))
#define F4W(p) (*reinterpret_cast<float4*>(p))

__device__ __forceinline__ void gload_lds16(const void* g, void* l) {
  __builtin_amdgcn_global_load_lds((const __attribute__((address_space(1))) void*)g,
                                   (__attribute__((address_space(3))) void*)l, 16, 0, 0);
}

__device__ __forceinline__ float sigmoidf_fast(float x) { return 1.f / (1.f + __expf(-x)); }
__device__ __forceinline__ float siluf(float x) { return x * sigmoidf_fast(x); }

__device__ __forceinline__ float allreduce64(float v) {
#pragma unroll
  for (int m = 1; m < 64; m <<= 1) v += __shfl_xor(v, m, 64);
  return v;
}

__device__ __forceinline__ bfx4_t to_bf4(float4 v) {
  bfx4_t o; o[0] = (__bf16)v.x; o[1] = (__bf16)v.y; o[2] = (__bf16)v.z; o[3] = (__bf16)v.w;
  return o;
}

__device__ __forceinline__ uint32_t bf2pack(float a, float b) {
  union { __bf16 h[2]; uint32_t u; } x;
  x.h[0] = (__bf16)a; x.h[1] = (__bf16)b; return x.u;
}

// ---------------- conversions ----------------
__global__ __launch_bounds__(256) void cvt_f32_bf16(const float* __restrict__ in,
                                                    __bf16* __restrict__ out) {
  int i = blockIdx.x * 256 + threadIdx.x;
  float4 v = reinterpret_cast<const float4*>(in)[i];
  reinterpret_cast<bfx4_t*>(out)[i] = to_bf4(v);
}

__global__ __launch_bounds__(256) void cvt_weights(const float* __restrict__ wqkv,
                                                   const float* __restrict__ wab,
                                                   __bf16* __restrict__ Wb) {
  int i = blockIdx.x * 256 + threadIdx.x;
  int e = i * 4;
  int row = e >> 10, col = e & 1023;
  float4 v;
  if (row < 3072)      v = *reinterpret_cast<const float4*>(wqkv + e);
  else if (row < 4128) v = *reinterpret_cast<const float4*>(wab + ((row - 3072) << 10) + col);
  else                 v = make_float4(0.f, 0.f, 0.f, 0.f);
  reinterpret_cast<bfx4_t*>(Wb)[i] = to_bf4(v);
}

// ---------------- bf16 MFMA GEMM: C[M][N] = A[M][K] * B[N][K]^T ----------------
// tn-major tile mapping: tm = bid&31, tn = bid>>5. XCD = bid%8 = tm%8 ->
// each XCD's A working set is 4 fixed panels (L2-resident); B panels are read
// by all XCDs concurrently -> served from L3 after first HBM fetch.
__global__ __launch_bounds__(256, 2) void gemm_bt(const __bf16* __restrict__ A,
                                                  const __bf16* __restrict__ Bm,
                                                  float* __restrict__ C,
                                                  int K, int lda, int ldb, int ldc) {
  __shared__ __align__(16) __bf16 As[128 * 64];
  __shared__ __align__(16) __bf16 Bs[128 * 64];
  const int tid = threadIdx.x;
  const int w = tid >> 6, lane = tid & 63;
  const int tm = blockIdx.x & 31, tn = blockIdx.x >> 5;
  const int wr = w >> 1, wc = w & 1;
  const int srow = lane >> 3, scol = (lane & 7) * 8;

  f32x4_t acc[4][4];
#pragma unroll
  for (int i = 0; i < 4; i++)
#pragma unroll
    for (int j = 0; j < 4; j++) acc[i][j] = f32x4_t{0.f, 0.f, 0.f, 0.f};

  const __bf16* Abase = A + (size_t)(tm * 128 + srow) * lda + scol;
  const __bf16* Bbase = Bm + (size_t)(tn * 128 + srow) * ldb + scol;

  for (int kk = 0; kk < K; kk += 64) {
#pragma unroll
    for (int r = 0; r < 4; r++) {
      const int rr = (r * 4 + w) * 8;
      gload_lds16(Abase + (size_t)rr * lda + kk, &As[rr * 64]);
      gload_lds16(Bbase + (size_t)rr * ldb + kk, &Bs[rr * 64]);
    }
    __syncthreads();
#pragma unroll
    for (int ks = 0; ks < 2; ks++) {
      bfx8_t af[4], bfr[4];
#pragma unroll
      for (int i = 0; i < 4; i++) {
        af[i]  = *reinterpret_cast<const bfx8_t*>(&As[(wr * 64 + i * 16 + (lane & 15)) * 64 + ks * 32 + (lane >> 4) * 8]);
        bfr[i] = *reinterpret_cast<const bfx8_t*>(&Bs[(wc * 64 + i * 16 + (lane & 15)) * 64 + ks * 32 + (lane >> 4) * 8]);
      }
#pragma unroll
      for (int i = 0; i < 4; i++)
#pragma unroll
        for (int j = 0; j < 4; j++)
          acc[i][j] = __builtin_amdgcn_mfma_f32_16x16x32_bf16(af[i], bfr[j], acc[i][j], 0, 0, 0);
    }
    __syncthreads();
  }
  const int crow = tm * 128 + wr * 64 + (lane >> 4) * 4;
  const int ccol = tn * 128 + wc * 64 + (lane & 15);
#pragma unroll
  for (int i = 0; i < 4; i++)
#pragma unroll
    for (int j = 0; j < 4; j++)
#pragma unroll
      for (int r = 0; r < 4; r++)
        C[(size_t)(crow + i * 16 + r) * ldc + ccol + j * 16] = acc[i][j][r];
}

// bf16-output variant (for Y): halves C-write traffic + downstream re-reads.
__global__ __launch_bounds__(256, 2) void gemm_bt_b16(const __bf16* __restrict__ A,
                                                      const __bf16* __restrict__ Bm,
                                                      __bf16* __restrict__ C,
                                                      int K, int lda, int ldb, int ldc) {
  __shared__ __align__(16) __bf16 As[128 * 64];
  __shared__ __align__(16) __bf16 Bs[128 * 64];
  const int tid = threadIdx.x;
  const int w = tid >> 6, lane = tid & 63;
  const int tm = blockIdx.x & 31, tn = blockIdx.x >> 5;
  const int wr = w >> 1, wc = w & 1;
  const int srow = lane >> 3, scol = (lane & 7) * 8;

  f32x4_t acc[4][4];
#pragma unroll
  for (int i = 0; i < 4; i++)
#pragma unroll
    for (int j = 0; j < 4; j++) acc[i][j] = f32x4_t{0.f, 0.f, 0.f, 0.f};

  const __bf16* Abase = A + (size_t)(tm * 128 + srow) * lda + scol;
  const __bf16* Bbase = Bm + (size_t)(tn * 128 + srow) * ldb + scol;

  for (int kk = 0; kk < K; kk += 64) {
#pragma unroll
    for (int r = 0; r < 4; r++) {
      const int rr = (r * 4 + w) * 8;
      gload_lds16(Abase + (size_t)rr * lda + kk, &As[rr * 64]);
      gload_lds16(Bbase + (size_t)rr * ldb + kk, &Bs[rr * 64]);
    }
    __syncthreads();
#pragma unroll
    for (int ks = 0; ks < 2; ks++) {
      bfx8_t af[4], bfr[4];
#pragma unroll
      for (int i = 0; i < 4; i++) {
        af[i]  = *reinterpret_cast<const bfx8_t*>(&As[(wr * 64 + i * 16 + (lane & 15)) * 64 + ks * 32 + (lane >> 4) * 8]);
        bfr[i] = *reinterpret_cast<const bfx8_t*>(&Bs[(wc * 64 + i * 16 + (lane & 15)) * 64 + ks * 32 + (lane >> 4) * 8]);
      }
#pragma unroll
      for (int i = 0; i < 4; i++)
#pragma unroll
        for (int j = 0; j < 4; j++)
          acc[i][j] = __builtin_amdgcn_mfma_f32_16x16x32_bf16(af[i], bfr[j], acc[i][j], 0, 0, 0);
    }
    __syncthreads();
  }
  const int crow = tm * 128 + wr * 64 + (lane >> 4) * 4;
  const int ccol = tn * 128 + wc * 64 + (lane & 15);
#pragma unroll
  for (int i = 0; i < 4; i++)
#pragma unroll
    for (int j = 0; j < 4; j++)
#pragma unroll
      for (int r = 0; r < 4; r++)
        C[(size_t)(crow + i * 16 + r) * ldc + ccol + j * 16] = (__bf16)acc[i][j][r];
}

// ---------------- conv + silu + l2norm + gates prep (Y now bf16) ----------------
__global__ __launch_bounds__(256) void prep_kernel(
    const __bf16* __restrict__ Y, const float* __restrict__ w_conv,
    const float* __restrict__ A_log, const float* __restrict__ dt_bias,
    float* __restrict__ qs, float* __restrict__ ks_, float* __restrict__ vs,
    float* __restrict__ gbuf, float* __restrict__ bbuf) {
  const int blk = blockIdx.x;  // b*2048 + s
  const int b = blk >> 11, s = blk & 2047;
  const int tid = threadIdx.x;
  const int w = tid >> 6, lane = tid & 63;

  float x[12];
#pragma unroll
  for (int j = 0; j < 12; j++) {
    const int c = tid + 256 * j;
    const float4 wc = *reinterpret_cast<const float4*>(w_conv + c * 4);
    const float* wcp = reinterpret_cast<const float*>(&wc);
    float acc = 0.f;
#pragma unroll
    for (int i = 0; i < 4; i++) {
      const int r = s - 3 + i;
      const float v = (r >= 0) ? (float)Y[(size_t)(b * 2048 + r) * NPAD + c] : 0.f;
      acc = fmaf(v, wcp[i], acc);
    }
    x[j] = siluf(acc);
  }

#pragma unroll
  for (int j = 0; j < 4; j++) {
    const float sq = allreduce64(x[j] * x[j]);
    const float sk = allreduce64(x[j + 4] * x[j + 4]);
    const float rq = rsqrtf(sq + 1e-6f) * 0.125f;  // fold DK^-0.5 into q
    const float rk = rsqrtf(sk + 1e-6f);
    const int head = 4 * j + w;
    const size_t base = ((size_t)(b * 16 + head) * 2048 + s) * 64 + lane;
    qs[base] = x[j] * rq;
    ks_[base] = x[j + 4] * rk;
    vs[base] = x[8 + j];
  }

  const __bf16* yab = Y + (size_t)blk * NPAD + 3072;
  if (tid < 16) {
    float a = (float)yab[tid] + dt_bias[tid];
    float sp = (a > 20.f) ? a : log1pf(expf(a));
    gbuf[(size_t)(b * 16 + tid) * 2048 + s] = -expf(A_log[tid]) * sp;  // raw g
  } else if (tid < 32) {
    int t = tid - 16;
    bbuf[(size_t)(b * 16 + t) * 2048 + s] = 1.f / (1.f + expf(-(float)yab[16 + t]));
  }
}

// ================= chunked WY delta rule =================
// chunk C=64. task = bh*32 + chunk. MFMA (bf16 in, fp32 acc) for all 64^3
// products; substitution / gating / recurrence stay fp32.

// Kernel A: At = gated KK^T (MFMA) -> forward substitution (fp32) ->
// Dv,W out; M = Kd^T W, PT = Dv^T Kd (MFMA). Mg stored pre-swizzled for chunkB.
__global__ __launch_bounds__(256, 3) void chunkA(
    const float* __restrict__ ks_, const float* __restrict__ vs,
    const float* __restrict__ gbuf, const float* __restrict__ bbuf,
    float* __restrict__ Dvg, __bf16* __restrict__ Wgb,
    float* __restrict__ Mg, float* __restrict__ PTg, float* __restrict__ egb) {
  const int task = blockIdx.x, bh = task >> 5, cc = task & 31;
  const int tid = threadIdx.x;
  const int w = tid >> 6, lane = tid & 63;
  __shared__ __align__(16) char regA[18432];   // At fp32 [64][68] -> XTb bf16 [128][72]
  __shared__ __align__(16) float Ks[64 * 68];
  __shared__ __align__(16) char regC[9216];    // Kb bf16 [64][72] -> KdTb bf16 [64][72]
  __shared__ float xbc[2][128];
  __shared__ float gcs[64], bcs[64];
  float* At   = (float*)regA;
  __bf16* XTb = (__bf16*)regA;   // [ci][s]: ci 0..63 = Dv cols (v), 64..127 = W cols (d)
  __bf16* Kb   = (__bf16*)regC;  // [s][d]
  __bf16* KdTb = (__bf16*)regC;  // [d][s]

  const size_t cb = ((size_t)bh * 2048 + cc * 64) * 64;
  // P0: stage K (fp32+bf16), cumsum g, beta
  { int s = tid >> 2, d0 = (tid & 3) * 16;
#pragma unroll
    for (int i = 0; i < 4; i++) {
      float4 v = F4(&ks_[cb + (size_t)s * 64 + d0 + 4 * i]);
      F4W(&Ks[s * 68 + d0 + 4 * i]) = v;
      *reinterpret_cast<bfx4_t*>(&Kb[s * 72 + d0 + 4 * i]) = to_bf4(v);
    }
  }
  if (tid < 64) {
    float gv = gbuf[(size_t)bh * 2048 + cc * 64 + tid];
    bcs[tid] = bbuf[(size_t)bh * 2048 + cc * 64 + tid];
#pragma unroll
    for (int off = 1; off < 64; off <<= 1) {
      float n = __shfl_up(gv, (unsigned)off, 64);
      if (tid >= off) gv += n;
    }
    gcs[tid] = gv;
  }
  __syncthreads();

  // prefetch v for RHS (latency hides under P1 MFMA)
  const int hh = tid >> 7, cI = tid & 127;
  float vpre[32];
  if (cI < 64) {
#pragma unroll
    for (int r = 0; r < 32; r++)
      vpre[r] = vs[cb + (size_t)(hh * 32 + r) * 64 + cI];
  }

  // P1: At[s][t] = (t>s)? beta_t*exp(gc_t-gc_s)*(k_t.k_s) : 0  via MFMA
  {
    bfx8_t aS[2];
#pragma unroll
    for (int kh = 0; kh < 2; kh++)
      aS[kh] = *reinterpret_cast<const bfx8_t*>(&Kb[(16 * w + (lane & 15)) * 72 + kh * 32 + (lane >> 4) * 8]);
#pragma unroll
    for (int j = 0; j < 4; j++) {
      if (j < w) {  // strictly-lower tiles: zero
#pragma unroll
        for (int r = 0; r < 4; r++)
          At[(16 * w + (lane >> 4) * 4 + r) * 68 + 16 * j + (lane & 15)] = 0.f;
      } else {
        f32x4_t acc = {0.f, 0.f, 0.f, 0.f};
#pragma unroll
        for (int kh = 0; kh < 2; kh++) {
          bfx8_t bS = *reinterpret_cast<const bfx8_t*>(&Kb[(16 * j + (lane & 15)) * 72 + kh * 32 + (lane >> 4) * 8]);
          acc = __builtin_amdgcn_mfma_f32_16x16x32_bf16(aS[kh], bS, acc, 0, 0, 0);
        }
        const int t = 16 * j + (lane & 15);
        const float bt = bcs[t], gt = gcs[t];
#pragma unroll
        for (int r = 0; r < 4; r++) {
          const int s = 16 * w + (lane >> 4) * 4 + r;
          At[s * 68 + t] = (t > s) ? bt * __expf(gt - gcs[s]) * acc[r] : 0.f;
        }
      }
    }
  }
  __syncthreads();

  // P2: RHS init: X = [ beta*V | beta*exp(gc)*K ], thread = (hh, cI)
  float X[32];
  if (cI < 64) {
#pragma unroll
    for (int r = 0; r < 32; r++) X[r] = bcs[hh * 32 + r] * vpre[r];
  } else {
#pragma unroll
    for (int r = 0; r < 32; r++) {
      int s = hh * 32 + r;
      X[r] = bcs[s] * __expf(gcs[s]) * Ks[s * 68 + (cI - 64)];
    }
  }

  // P3: forward substitution (fp32; At diag/lower zeros -> unpredicated ok)
#pragma unroll
  for (int s = 0; s < 64; ++s) {
    if (hh == (s >> 5)) xbc[s & 1][cI] = X[s & 31];
    __syncthreads();
    float xs = xbc[s & 1][cI];
    const float* atrow = &At[s * 68 + hh * 32];
#pragma unroll
    for (int j = 0; j < 8; j++) {
      float4 a4 = F4(atrow + 4 * j);
      X[4 * j + 0] = fmaf(-a4.x, xs, X[4 * j + 0]);
      X[4 * j + 1] = fmaf(-a4.y, xs, X[4 * j + 1]);
      X[4 * j + 2] = fmaf(-a4.z, xs, X[4 * j + 2]);
      X[4 * j + 3] = fmaf(-a4.w, xs, X[4 * j + 3]);
    }
  }
  __syncthreads();  // all At reads done -> regA reusable as XTb

  // P5: Dv/W global writes (from regs); XTb transposed bf16; KdTb build
  if (cI < 64) {
#pragma unroll
    for (int r = 0; r < 32; r++)
      Dvg[(size_t)task * 4096 + (size_t)(hh * 32 + r) * 64 + cI] = X[r];
  } else {
#pragma unroll
    for (int r = 0; r < 32; r++)
      Wgb[(size_t)task * 4096 + (size_t)(hh * 32 + r) * 64 + (cI - 64)] = (__bf16)X[r];
  }
#pragma unroll
  for (int i = 0; i < 16; i++)
    *reinterpret_cast<uint32_t*>(&XTb[cI * 72 + hh * 32 + 2 * i]) = bf2pack(X[2 * i], X[2 * i + 1]);
  { // KdTb[d][s] = bf16( K[s][d] * exp(gc_63 - gc_s) )
    int s = tid >> 2, d0 = (tid & 3) * 16;
    float ek = __expf(gcs[63] - gcs[s]);
#pragma unroll
    for (int i = 0; i < 4; i++) {
      float4 v = F4(&Ks[s * 68 + d0 + 4 * i]);
      KdTb[(d0 + 4 * i + 0) * 72 + s] = (__bf16)(v.x * ek);
      KdTb[(d0 + 4 * i + 1) * 72 + s] = (__bf16)(v.y * ek);
      KdTb[(d0 + 4 * i + 2) * 72 + s] = (__bf16)(v.z * ek);
      KdTb[(d0 + 4 * i + 3) * 72 + s] = (__bf16)(v.w * ek);
    }
  }
  __syncthreads();

  // P6: M[d][e] = sum_s Kd[s][d]W[s][e]; PT[v][d] = sum_s Dv[s][v]Kd[s][d]
  {
    bfx8_t aM[2], aP[2];
#pragma unroll
    for (int kh = 0; kh < 2; kh++) {
      aM[kh] = *reinterpret_cast<const bfx8_t*>(&KdTb[(16 * w + (lane & 15)) * 72 + kh * 32 + (lane >> 4) * 8]);
      aP[kh] = *reinterpret_cast<const bfx8_t*>(&XTb [(16 * w + (lane & 15)) * 72 + kh * 32 + (lane >> 4) * 8]);
    }
#pragma unroll
    for (int j = 0; j < 4; j++) {
      f32x4_t mAcc = {0.f, 0.f, 0.f, 0.f}, pAcc = {0.f, 0.f, 0.f, 0.f};
#pragma unroll
      for (int kh = 0; kh < 2; kh++) {
        bfx8_t bW = *reinterpret_cast<const bfx8_t*>(&XTb [(64 + 16 * j + (lane & 15)) * 72 + kh * 32 + (lane >> 4) * 8]);
        bfx8_t bK = *reinterpret_cast<const bfx8_t*>(&KdTb[(16 * j + (lane & 15)) * 72 + kh * 32 + (lane >> 4) * 8]);
        mAcc = __builtin_amdgcn_mfma_f32_16x16x32_bf16(aM[kh], bW, mAcc, 0, 0, 0);
        pAcc = __builtin_amdgcn_mfma_f32_16x16x32_bf16(aP[kh], bK, pAcc, 0, 0, 0);
      }
#pragma unroll
      for (int r = 0; r < 4; r++) {
        const int drow = 16 * w + (lane >> 4) * 4 + r;  // M row d / PT row v
        const int ecol = 16 * j + (lane & 15);          // M col e / PT col d
        const int ge = ecol >> 2;
        const int ges = (ge & 8) | ((ge & 7) ^ (drow & 7));  // chunkB swizzle
        Mg [(size_t)task * 4096 + drow * 64 + ges * 4 + (ecol & 3)] = mAcc[r];
        PTg[(size_t)task * 4096 + drow * 64 + ecol] = pAcc[r];
      }
    }
  }
  if (tid == 0) egb[task] = __expf(gcs[63]);
}

// Kernel B: sequential over chunks (unchanged).
__global__ __launch_bounds__(64) void chunkB(
    const float* __restrict__ Mg, const float* __restrict__ PTg,
    const float* __restrict__ egb, float* __restrict__ hTg) {
  const int bh = blockIdx.x & 31, vq = blockIdx.x >> 5;
  const int tid = threadIdx.x;
  const int tv = tid >> 4, td = tid & 15;
  __shared__ __align__(16) float Ml[2][64 * 64];
  __shared__ __align__(16) float hT[8 * 68];

  float h[2][4];
#pragma unroll
  for (int r = 0; r < 2; r++)
#pragma unroll
    for (int c = 0; c < 4; c++) h[r][c] = 0.f;
#pragma unroll
  for (int r = 0; r < 2; r++)
#pragma unroll
    for (int c = 0; c < 4; c++) hT[(tv * 2 + r) * 68 + c * 16 + td] = 0.f;

  const char* mb = (const char*)(Mg + (size_t)bh * 32 * 4096);
#pragma unroll
  for (int j = 0; j < 16; j++)
    gload_lds16(mb + j * 1024 + tid * 16, &Ml[0][j * 256]);

  const int kk = (td & 7) << 2;
  int cur = 0;
  for (int cch = 0; cch < 32; ++cch) {
    const size_t tb = ((size_t)bh * 32 + cch) * 4096;
    asm volatile("s_waitcnt vmcnt(0)" ::: "memory");
    __builtin_amdgcn_sched_barrier(0);
    if (cch < 31) {
#pragma unroll
      for (int j = 0; j < 16; j++)
        gload_lds16(mb + (size_t)(cch + 1) * 16384 + j * 1024 + tid * 16,
                    &Ml[cur ^ 1][j * 256]);
    }
    float ptc[2][4];
#pragma unroll
    for (int r = 0; r < 2; r++)
#pragma unroll
      for (int c = 0; c < 4; c++)
        ptc[r][c] = PTg[tb + (size_t)(vq * 8 + tv * 2 + r) * 64 + c * 16 + td];
    const float egc = egb[bh * 32 + cch];
#pragma unroll
    for (int r = 0; r < 2; r++)
#pragma unroll
      for (int c = 0; c < 4; c++)
        hTg[tb + (size_t)(vq * 8 + tv * 2 + r) * 64 + c * 16 + td] = h[r][c];
    float acc[2][4] = {};
#pragma unroll
    for (int e0 = 0; e0 < 64; e0 += 4) {
      const int es = (e0 & 32) | ((e0 & 28) ^ kk);
      float4 h4[2], m4[4];
#pragma unroll
      for (int r = 0; r < 2; r++) h4[r] = F4(&hT[(tv * 2 + r) * 68 + e0]);
#pragma unroll
      for (int c = 0; c < 4; c++) m4[c] = F4(&Ml[cur][(c * 16 + td) * 64 + es]);
#pragma unroll
      for (int r = 0; r < 2; r++)
#pragma unroll
        for (int c = 0; c < 4; c++) {
          acc[r][c] = fmaf(h4[r].x, m4[c].x, acc[r][c]);
          acc[r][c] = fmaf(h4[r].y, m4[c].y, acc[r][c]);
          acc[r][c] = fmaf(h4[r].z, m4[c].z, acc[r][c]);
          acc[r][c] = fmaf(h4[r].w, m4[c].w, acc[r][c]);
        }
    }
#pragma unroll
    for (int r = 0; r < 2; r++)
#pragma unroll
      for (int c = 0; c < 4; c++)
        h[r][c] = egc * h[r][c] - acc[r][c] + ptc[r][c];
#pragma unroll
    for (int r = 0; r < 2; r++)
#pragma unroll
      for (int c = 0; c < 4; c++) hT[(tv * 2 + r) * 68 + c * 16 + td] = h[r][c];
    cur ^= 1;
  }
}

// Kernel C: O = diag(exp(gc)) Q h0 + Sm * (Dv - W h0), all products via MFMA.
__global__ __launch_bounds__(256, 3) void chunkC(
    const float* __restrict__ qs, const float* __restrict__ ks_,
    const float* __restrict__ gbuf, const float* __restrict__ Dvg,
    const __bf16* __restrict__ Wgb, const float* __restrict__ hTg,
    float* __restrict__ o_raw) {
  const int task = blockIdx.x, bh = task >> 5, cc = task & 31;
  const int b = bh >> 4, hd = bh & 15;
  const int tid = threadIdx.x;
  const int w = tid >> 6, lane = tid & 63;
  __shared__ __align__(16) __bf16 cQb[64 * 72];  // Q rows
  __shared__ __align__(16) char  regK[9216];     // cKb [s][d] -> dTb [v][s]
  __shared__ __align__(16) __bf16 cWb[64 * 72];  // W rows
  __shared__ __align__(16) __bf16 hTb[64 * 72];  // hT rows (v-major)
  __shared__ __align__(16) __bf16 Smb[64 * 72];  // gated scores [t][s]
  __shared__ float gcs[64];
  __bf16* cKb = (__bf16*)regK;
  __bf16* dTb = (__bf16*)regK;

  const size_t cb = ((size_t)bh * 2048 + cc * 64) * 64;
  // stage Q, K, hT (fp32->bf16), W (bf16 copy), cumsum g
  { int s = tid >> 2, d0 = (tid & 3) * 16;
#pragma unroll
    for (int i = 0; i < 4; i++) {
      *reinterpret_cast<bfx4_t*>(&cQb[s * 72 + d0 + 4 * i]) = to_bf4(F4(&qs [cb + (size_t)s * 64 + d0 + 4 * i]));
      *reinterpret_cast<bfx4_t*>(&cKb[s * 72 + d0 + 4 * i]) = to_bf4(F4(&ks_[cb + (size_t)s * 64 + d0 + 4 * i]));
      *reinterpret_cast<bfx4_t*>(&hTb[s * 72 + d0 + 4 * i]) = to_bf4(F4(&hTg[(size_t)task * 4096 + (size_t)s * 64 + d0 + 4 * i]));
    }
    const bfx8_t* wp = reinterpret_cast<const bfx8_t*>(&Wgb[(size_t)task * 4096 + (size_t)s * 64 + d0]);
    *reinterpret_cast<bfx8_t*>(&cWb[s * 72 + d0]) = wp[0];
    *reinterpret_cast<bfx8_t*>(&cWb[s * 72 + d0 + 8]) = wp[1];
  }
  if (tid < 64) {
    float gv = gbuf[(size_t)bh * 2048 + cc * 64 + tid];
#pragma unroll
    for (int off = 1; off < 64; off <<= 1) {
      float n = __shfl_up(gv, (unsigned)off, 64);
      if (tid >= off) gv += n;
    }
    gcs[tid] = gv;
  }
  __syncthreads();

  // P1: S = QK^T (gate -> Smb bf16) and QH = Q hT^T (regs), wave w owns t-tile w
  f32x4_t qh[4];
  {
    bfx8_t aQ[2];
#pragma unroll
    for (int kh = 0; kh < 2; kh++)
      aQ[kh] = *reinterpret_cast<const bfx8_t*>(&cQb[(16 * w + (lane & 15)) * 72 + kh * 32 + (lane >> 4) * 8]);
#pragma unroll
    for (int j = 0; j < 4; j++) {
      f32x4_t sAcc = {0.f, 0.f, 0.f, 0.f};
      qh[j] = f32x4_t{0.f, 0.f, 0.f, 0.f};
#pragma unroll
      for (int kh = 0; kh < 2; kh++) {
        bfx8_t bK = *reinterpret_cast<const bfx8_t*>(&cKb[(16 * j + (lane & 15)) * 72 + kh * 32 + (lane >> 4) * 8]);
        bfx8_t bH = *reinterpret_cast<const bfx8_t*>(&hTb[(16 * j + (lane & 15)) * 72 + kh * 32 + (lane >> 4) * 8]);
        sAcc = __builtin_amdgcn_mfma_f32_16x16x32_bf16(aQ[kh], bK, sAcc, 0, 0, 0);
        qh[j] = __builtin_amdgcn_mfma_f32_16x16x32_bf16(aQ[kh], bH, qh[j], 0, 0, 0);
      }
      const int s = 16 * j + (lane & 15);
      const float gs = gcs[s];
#pragma unroll
      for (int r = 0; r < 4; r++) {
        const int t = 16 * w + (lane >> 4) * 4 + r;
        float sv = (s <= t) ? __expf(gcs[t] - gs) * sAcc[r] : 0.f;
        Smb[t * 72 + s] = (__bf16)sv;
      }
    }
  }
  __syncthreads();  // Smb visible; cKb reads done

  // P3: U = W hT^T; delta = Dv - U -> dTb[v][s] bf16 (over cKb region)
  {
    bfx8_t aW[2];
#pragma unroll
    for (int kh = 0; kh < 2; kh++)
      aW[kh] = *reinterpret_cast<const bfx8_t*>(&cWb[(16 * w + (lane & 15)) * 72 + kh * 32 + (lane >> 4) * 8]);
#pragma unroll
    for (int j = 0; j < 4; j++) {
      f32x4_t u = {0.f, 0.f, 0.f, 0.f};
#pragma unroll
      for (int kh = 0; kh < 2; kh++) {
        bfx8_t bH = *reinterpret_cast<const bfx8_t*>(&hTb[(16 * j + (lane & 15)) * 72 + kh * 32 + (lane >> 4) * 8]);
        u = __builtin_amdgcn_mfma_f32_16x16x32_bf16(aW[kh], bH, u, 0, 0, 0);
      }
      const int v = 16 * j + (lane & 15);
#pragma unroll
      for (int r = 0; r < 4; r++) {
        const int s = 16 * w + (lane >> 4) * 4 + r;
        float dl = Dvg[(size_t)task * 4096 + (size_t)s * 64 + v] - u[r];
        dTb[v * 72 + s] = (__bf16)dl;
      }
    }
  }
  __syncthreads();

  // P4: O = exp(gc_t)*QH + Sm*delta; write o_raw
  {
    bfx8_t aS2[2];
#pragma unroll
    for (int kh = 0; kh < 2; kh++)
      aS2[kh] = *reinterpret_cast<const bfx8_t*>(&Smb[(16 * w + (lane & 15)) * 72 + kh * 32 + (lane >> 4) * 8]);
    float esc[4];
#pragma unroll
    for (int r = 0; r < 4; r++) esc[r] = __expf(gcs[16 * w + (lane >> 4) * 4 + r]);
#pragma unroll
    for (int j = 0; j < 4; j++) {
#pragma unroll
      for (int r = 0; r < 4; r++) qh[j][r] *= esc[r];
#pragma unroll
      for (int kh = 0; kh < 2; kh++) {
        bfx8_t bD = *reinterpret_cast<const bfx8_t*>(&dTb[(16 * j + (lane & 15)) * 72 + kh * 32 + (lane >> 4) * 8]);
        qh[j] = __builtin_amdgcn_mfma_f32_16x16x32_bf16(aS2[kh], bD, qh[j], 0, 0, 0);
      }
      const int v = 16 * j + (lane & 15);
#pragma unroll
      for (int r = 0; r < 4; r++) {
        const int t = 16 * w + (lane >> 4) * 4 + r;
        o_raw[(((size_t)b * 2048 + cc * 64 + t) * 16 + hd) * 64 + v] = qh[j][r];
      }
    }
  }
}

// ---------------- gate * silu + per-head RMS norm -> bf16 (Y bf16) ----------------
__global__ __launch_bounds__(256) void gate_rms(
    const float* __restrict__ o_raw, const __bf16* __restrict__ Y,
    const float* __restrict__ rms_w, __bf16* __restrict__ o2b) {
  const int blk = blockIdx.x;
  const int tid = threadIdx.x;
  const int H = tid >> 4, d0 = (tid & 15) * 4;
  const size_t ob = (size_t)blk * 1024 + H * 64 + d0;
  float4 o = *reinterpret_cast<const float4*>(o_raw + ob);
  bfx4_t gb = *reinterpret_cast<const bfx4_t*>(Y + (size_t)blk * NPAD + 3104 + H * 64 + d0);
  float o2[4];
  o2[0] = o.x * siluf((float)gb[0]); o2[1] = o.y * siluf((float)gb[1]);
  o2[2] = o.z * siluf((float)gb[2]); o2[3] = o.w * siluf((float)gb[3]);
  float ssq = o2[0] * o2[0] + o2[1] * o2[1] + o2[2] * o2[2] + o2[3] * o2[3];
  ssq += __shfl_xor(ssq, 1, 64);
  ssq += __shfl_xor(ssq, 2, 64);
  ssq += __shfl_xor(ssq, 4, 64);
  ssq += __shfl_xor(ssq, 8, 64);
  const float scale = rsqrtf(ssq * (1.f / 64.f) + 1e-5f);
  bfx4_t r;
#pragma unroll
  for (int i = 0; i < 4; i++) r[i] = (__bf16)(o2[i] * scale * rms_w[d0 + i]);
  *reinterpret_cast<bfx4_t*>(o2b + ob) = r;
}

// ---------------- launch ----------------
extern "C" void kernel_launch(void* const* d_in, const int* in_sizes, int n_in,
                              void* d_out, int out_size, void* d_ws, size_t ws_size,
                              hipStream_t stream) {
  (void)in_sizes; (void)n_in; (void)out_size; (void)ws_size;
  const float* hidden = (const float*)d_in[0];
  const float* w_qkv  = (const float*)d_in[1];
  const float* w_ab   = (const float*)d_in[2];
  const float* w_conv = (const float*)d_in[3];
  const float* A_log  = (const float*)d_in[4];
  const float* dt_b   = (const float*)d_in[5];
  const float* rms_w  = (const float*)d_in[6];
  const float* w_o    = (const float*)d_in[7];
  float* out = (float*)d_out;

  char* ws = (char*)d_ws;
  size_t off = 0;
  auto alloc = [&](size_t bytes) { void* p = ws + off; off += (bytes + 255) & ~(size_t)255; return p; };
  __bf16* Xb   = (__bf16*)alloc((size_t)4096 * 1024 * 2);   // dead after gemm1
  __bf16* Wb   = (__bf16*)alloc((size_t)NPAD * 1024 * 2);   // dead after gemm1
  __bf16* Wob  = (__bf16*)alloc((size_t)1024 * 1024 * 2);
  __bf16* Y    = (__bf16*)alloc((size_t)4096 * NPAD * 2);   // bf16 Y
  float* qs    = (float*)alloc((size_t)32 * 2048 * 64 * 4);
  float* ks    = (float*)alloc((size_t)32 * 2048 * 64 * 4);
  float* vs    = (float*)alloc((size_t)32 * 2048 * 64 * 4);
  float* gbuf  = (float*)alloc((size_t)32 * 2048 * 4);
  float* bbuf  = (float*)alloc((size_t)32 * 2048 * 4);
  float* Dvg   = (float*)alloc((size_t)1024 * 4096 * 4);
  __bf16* Wgb  = (__bf16*)alloc((size_t)1024 * 4096 * 2);
  float* Mg    = (float*)alloc((size_t)1024 * 4096 * 4);
  float* PTg   = (float*)alloc((size_t)1024 * 4096 * 4);
  float* hTg   = (float*)alloc((size_t)1024 * 4096 * 4);
  float* egb   = (float*)alloc((size_t)1024 * 4);
  __bf16* o2b  = (__bf16*)alloc((size_t)4096 * 1024 * 2);
  // o_raw (16MB) aliases Xb+Wb (16.6MB): Xb/Wb dead after gemm1
  float* o_raw = (float*)Xb;

  cvt_f32_bf16<<<4096, 256, 0, stream>>>(hidden, Xb);
  cvt_weights<<<4224, 256, 0, stream>>>(w_qkv, w_ab, Wb);
  cvt_f32_bf16<<<1024, 256, 0, stream>>>(w_o, Wob);
  gemm_bt_b16<<<32 * 33, 256, 0, stream>>>(Xb, Wb, Y, 1024, 1024, 1024, NPAD);
  prep_kernel<<<4096, 256, 0, stream>>>(Y, w_conv, A_log, dt_b, qs, ks, vs, gbuf, bbuf);
  chunkA<<<1024, 256, 0, stream>>>(ks, vs, gbuf, bbuf, Dvg, Wgb, Mg, PTg, egb);
  chunkB<<<256, 64, 0, stream>>>(Mg, PTg, egb, hTg);
  chunkC<<<1024, 256, 0, stream>>>(qs, ks, gbuf, Dvg, Wgb, hTg, o_raw);
  gate_rms<<<4096, 256, 0, stream>>>(o_raw, Y, rms_w, o2b);
  gemm_bt<<<32 * 8, 256, 0, stream>>>(o2b, Wob, out, 1024, 1024, 1024, 1024);
}

// Round 8
// 324.421 us; speedup vs baseline: 1.1089x; 1.1089x over previous
//
#include <hip/hip_runtime.h>
#include <stdint.h>
#include <math.h>

#define NPAD 4224   // padded N for the fused qkv+ab GEMM (4128 -> 33*128)

typedef float  f32x4_t __attribute__((ext_vector_type(4)));
typedef __bf16 bfx8_t  __attribute__((ext_vector_type(8)));
typedef __bf16 bfx4_t  __attribute__((ext_vector_type(4)));

#define F4(p)  (*reinterpret_cast<const float4*>(p))
#define F4W(p) (*reinterpret_cast<float4*>(p))
#define BF8(p)  (*reinterpret_cast<const bfx8_t*>(p))
#define BF8W(p) (*reinterpret_cast<bfx8_t*>(p))

__device__ __forceinline__ void gload_lds16(const void* g, void* l) {
  __builtin_amdgcn_global_load_lds((const __attribute__((address_space(1))) void*)g,
                                   (__attribute__((address_space(3))) void*)l, 16, 0, 0);
}

__device__ __forceinline__ float sigmoidf_fast(float x) { return 1.f / (1.f + __expf(-x)); }
__device__ __forceinline__ float siluf(float x) { return x * sigmoidf_fast(x); }

__device__ __forceinline__ bfx4_t to_bf4(float4 v) {
  bfx4_t o; o[0] = (__bf16)v.x; o[1] = (__bf16)v.y; o[2] = (__bf16)v.z; o[3] = (__bf16)v.w;
  return o;
}

__device__ __forceinline__ uint32_t bf2pack(float a, float b) {
  union { __bf16 h[2]; uint32_t u; } x;
  x.h[0] = (__bf16)a; x.h[1] = (__bf16)b; return x.u;
}

// ---------------- conversions ----------------
__global__ __launch_bounds__(256) void cvt_f32_bf16(const float* __restrict__ in,
                                                    __bf16* __restrict__ out) {
  int i = blockIdx.x * 256 + threadIdx.x;
  float4 v = reinterpret_cast<const float4*>(in)[i];
  reinterpret_cast<bfx4_t*>(out)[i] = to_bf4(v);
}

__global__ __launch_bounds__(256) void cvt_weights(const float* __restrict__ wqkv,
                                                   const float* __restrict__ wab,
                                                   __bf16* __restrict__ Wb) {
  int i = blockIdx.x * 256 + threadIdx.x;
  int e = i * 4;
  int row = e >> 10, col = e & 1023;
  float4 v;
  if (row < 3072)      v = *reinterpret_cast<const float4*>(wqkv + e);
  else if (row < 4128) v = *reinterpret_cast<const float4*>(wab + ((row - 3072) << 10) + col);
  else                 v = make_float4(0.f, 0.f, 0.f, 0.f);
  reinterpret_cast<bfx4_t*>(Wb)[i] = to_bf4(v);
}

// ---------------- bf16 MFMA GEMM: C[M][N] = A[M][K] * B[N][K]^T ----------------
// tn-major tile mapping: tm = bid&31, tn = bid>>5 -> per-XCD A panels L2-resident.
__global__ __launch_bounds__(256, 2) void gemm_bt(const __bf16* __restrict__ A,
                                                  const __bf16* __restrict__ Bm,
                                                  float* __restrict__ C,
                                                  int K, int lda, int ldb, int ldc) {
  __shared__ __align__(16) __bf16 As[128 * 64];
  __shared__ __align__(16) __bf16 Bs[128 * 64];
  const int tid = threadIdx.x;
  const int w = tid >> 6, lane = tid & 63;
  const int tm = blockIdx.x & 31, tn = blockIdx.x >> 5;
  const int wr = w >> 1, wc = w & 1;
  const int srow = lane >> 3, scol = (lane & 7) * 8;

  f32x4_t acc[4][4];
#pragma unroll
  for (int i = 0; i < 4; i++)
#pragma unroll
    for (int j = 0; j < 4; j++) acc[i][j] = f32x4_t{0.f, 0.f, 0.f, 0.f};

  const __bf16* Abase = A + (size_t)(tm * 128 + srow) * lda + scol;
  const __bf16* Bbase = Bm + (size_t)(tn * 128 + srow) * ldb + scol;

  for (int kk = 0; kk < K; kk += 64) {
#pragma unroll
    for (int r = 0; r < 4; r++) {
      const int rr = (r * 4 + w) * 8;
      gload_lds16(Abase + (size_t)rr * lda + kk, &As[rr * 64]);
      gload_lds16(Bbase + (size_t)rr * ldb + kk, &Bs[rr * 64]);
    }
    __syncthreads();
#pragma unroll
    for (int ks = 0; ks < 2; ks++) {
      bfx8_t af[4], bfr[4];
#pragma unroll
      for (int i = 0; i < 4; i++) {
        af[i]  = BF8(&As[(wr * 64 + i * 16 + (lane & 15)) * 64 + ks * 32 + (lane >> 4) * 8]);
        bfr[i] = BF8(&Bs[(wc * 64 + i * 16 + (lane & 15)) * 64 + ks * 32 + (lane >> 4) * 8]);
      }
#pragma unroll
      for (int i = 0; i < 4; i++)
#pragma unroll
        for (int j = 0; j < 4; j++)
          acc[i][j] = __builtin_amdgcn_mfma_f32_16x16x32_bf16(af[i], bfr[j], acc[i][j], 0, 0, 0);
    }
    __syncthreads();
  }
  const int crow = tm * 128 + wr * 64 + (lane >> 4) * 4;
  const int ccol = tn * 128 + wc * 64 + (lane & 15);
#pragma unroll
  for (int i = 0; i < 4; i++)
#pragma unroll
    for (int j = 0; j < 4; j++)
#pragma unroll
      for (int r = 0; r < 4; r++)
        C[(size_t)(crow + i * 16 + r) * ldc + ccol + j * 16] = acc[i][j][r];
}

// bf16-output variant (for Y).
__global__ __launch_bounds__(256, 2) void gemm_bt_b16(const __bf16* __restrict__ A,
                                                      const __bf16* __restrict__ Bm,
                                                      __bf16* __restrict__ C,
                                                      int K, int lda, int ldb, int ldc) {
  __shared__ __align__(16) __bf16 As[128 * 64];
  __shared__ __align__(16) __bf16 Bs[128 * 64];
  const int tid = threadIdx.x;
  const int w = tid >> 6, lane = tid & 63;
  const int tm = blockIdx.x & 31, tn = blockIdx.x >> 5;
  const int wr = w >> 1, wc = w & 1;
  const int srow = lane >> 3, scol = (lane & 7) * 8;

  f32x4_t acc[4][4];
#pragma unroll
  for (int i = 0; i < 4; i++)
#pragma unroll
    for (int j = 0; j < 4; j++) acc[i][j] = f32x4_t{0.f, 0.f, 0.f, 0.f};

  const __bf16* Abase = A + (size_t)(tm * 128 + srow) * lda + scol;
  const __bf16* Bbase = Bm + (size_t)(tn * 128 + srow) * ldb + scol;

  for (int kk = 0; kk < K; kk += 64) {
#pragma unroll
    for (int r = 0; r < 4; r++) {
      const int rr = (r * 4 + w) * 8;
      gload_lds16(Abase + (size_t)rr * lda + kk, &As[rr * 64]);
      gload_lds16(Bbase + (size_t)rr * ldb + kk, &Bs[rr * 64]);
    }
    __syncthreads();
#pragma unroll
    for (int ks = 0; ks < 2; ks++) {
      bfx8_t af[4], bfr[4];
#pragma unroll
      for (int i = 0; i < 4; i++) {
        af[i]  = BF8(&As[(wr * 64 + i * 16 + (lane & 15)) * 64 + ks * 32 + (lane >> 4) * 8]);
        bfr[i] = BF8(&Bs[(wc * 64 + i * 16 + (lane & 15)) * 64 + ks * 32 + (lane >> 4) * 8]);
      }
#pragma unroll
      for (int i = 0; i < 4; i++)
#pragma unroll
        for (int j = 0; j < 4; j++)
          acc[i][j] = __builtin_amdgcn_mfma_f32_16x16x32_bf16(af[i], bfr[j], acc[i][j], 0, 0, 0);
    }
    __syncthreads();
  }
  const int crow = tm * 128 + wr * 64 + (lane >> 4) * 4;
  const int ccol = tn * 128 + wc * 64 + (lane & 15);
#pragma unroll
  for (int i = 0; i < 4; i++)
#pragma unroll
    for (int j = 0; j < 4; j++)
#pragma unroll
      for (int r = 0; r < 4; r++)
        C[(size_t)(crow + i * 16 + r) * ldc + ccol + j * 16] = (__bf16)acc[i][j][r];
}

// ---------------- conv + silu + l2norm + gates prep v2 ----------------
// 384 threads; thread owns 8 CONSECUTIVE channels (c0 = tid*8) -> bfx8 loads.
// Head = 8 adjacent lanes -> 3-level shfl reduce. Outputs bf16.
__global__ __launch_bounds__(384) void prep_kernel(
    const __bf16* __restrict__ Y, const float* __restrict__ w_conv,
    const float* __restrict__ A_log, const float* __restrict__ dt_bias,
    __bf16* __restrict__ qs, __bf16* __restrict__ ks_, __bf16* __restrict__ vs,
    float* __restrict__ gbuf, float* __restrict__ bbuf) {
  const int blk = blockIdx.x;  // b*2048 + s
  const int b = blk >> 11, s = blk & 2047;
  const int tid = threadIdx.x;
  const int c0 = tid * 8;

  bfx8_t yv[4], z8;
#pragma unroll
  for (int q = 0; q < 8; q++) z8[q] = (__bf16)0.f;
#pragma unroll
  for (int i = 0; i < 4; i++) {
    const int r = s - 3 + i;
    yv[i] = (r >= 0) ? BF8(&Y[(size_t)(b * 2048 + r) * NPAD + c0]) : z8;
  }
  float x[8];
#pragma unroll
  for (int q = 0; q < 8; q++) {
    const float4 wq = F4(&w_conv[(c0 + q) * 4]);
    float acc = fmaf((float)yv[0][q], wq.x,
                fmaf((float)yv[1][q], wq.y,
                fmaf((float)yv[2][q], wq.z, (float)yv[3][q] * wq.w)));
    x[q] = siluf(acc);
  }

  const int sec = tid >> 7;            // 0=q, 1=k, 2=v
  const int head = (tid >> 3) & 15;
  const int d0 = (tid & 7) * 8;
  const size_t base = ((size_t)(b * 16 + head) * 2048 + s) * 64 + d0;
  bfx8_t outv;
  if (sec < 2) {
    float ss = 0.f;
#pragma unroll
    for (int q = 0; q < 8; q++) ss = fmaf(x[q], x[q], ss);
    ss += __shfl_xor(ss, 1, 64);
    ss += __shfl_xor(ss, 2, 64);
    ss += __shfl_xor(ss, 4, 64);
    float rs = rsqrtf(ss + 1e-6f);
    if (sec == 0) rs *= 0.125f;        // fold DK^-0.5 into q
#pragma unroll
    for (int q = 0; q < 8; q++) outv[q] = (__bf16)(x[q] * rs);
    if (sec == 0) BF8W(&qs[base]) = outv;
    else          BF8W(&ks_[base]) = outv;
  } else {
#pragma unroll
    for (int q = 0; q < 8; q++) outv[q] = (__bf16)x[q];
    BF8W(&vs[base]) = outv;
  }

  const __bf16* yab = Y + (size_t)blk * NPAD + 3072;
  if (tid < 16) {
    float a = (float)yab[tid] + dt_bias[tid];
    float sp = (a > 20.f) ? a : log1pf(expf(a));
    gbuf[(size_t)(b * 16 + tid) * 2048 + s] = -expf(A_log[tid]) * sp;  // raw g
  } else if (tid < 32) {
    int t = tid - 16;
    bbuf[(size_t)(b * 16 + t) * 2048 + s] = 1.f / (1.f + expf(-(float)yab[16 + t]));
  }
}

// ================= chunked WY delta rule =================
// chunk C=64. task = bh*32 + chunk. MFMA (bf16 in, fp32 acc) for all 64^3
// products; substitution / gating / recurrence stay fp32.

// Kernel A: At = gated KK^T (MFMA) -> forward substitution (fp32) ->
// Dv,W out; M = Kd^T W, PT = Dv^T Kd (MFMA). Mg stored pre-swizzled for chunkB.
__global__ __launch_bounds__(256, 4) void chunkA(
    const __bf16* __restrict__ ks_, const __bf16* __restrict__ vs,
    const float* __restrict__ gbuf, const float* __restrict__ bbuf,
    float* __restrict__ Dvg, __bf16* __restrict__ Wgb,
    float* __restrict__ Mg, float* __restrict__ PTg, float* __restrict__ egb) {
  const int task = blockIdx.x, bh = task >> 5, cc = task & 31;
  const int tid = threadIdx.x;
  const int w = tid >> 6, lane = tid & 63;
  __shared__ __align__(16) char regA[18432];   // At fp32 [64][68] -> XTb bf16 [128][72]
  __shared__ __align__(16) char regC[9216];    // Kb bf16 [64][72] -> KdTb bf16 [64][72]
  __shared__ float xbc[2][128];
  __shared__ float gcs[64], bcs[64];
  float* At   = (float*)regA;
  __bf16* XTb = (__bf16*)regA;   // [ci][s]: ci 0..63 = Dv cols (v), 64..127 = W cols (d)
  __bf16* Kb   = (__bf16*)regC;  // [s][d]
  __bf16* KdTb = (__bf16*)regC;  // [d][s]

  const size_t cb = ((size_t)bh * 2048 + cc * 64) * 64;
  // P0: stage Kb (keep staged values in regs for KdTb later)
  const int sr = tid >> 2, sd0 = (tid & 3) * 16;
  bfx8_t kst0 = BF8(&ks_[cb + (size_t)sr * 64 + sd0]);
  bfx8_t kst1 = BF8(&ks_[cb + (size_t)sr * 64 + sd0 + 8]);
  BF8W(&Kb[sr * 72 + sd0]) = kst0;
  BF8W(&Kb[sr * 72 + sd0 + 8]) = kst1;
  if (tid < 64) {
    float gv = gbuf[(size_t)bh * 2048 + cc * 64 + tid];
    bcs[tid] = bbuf[(size_t)bh * 2048 + cc * 64 + tid];
#pragma unroll
    for (int off = 1; off < 64; off <<= 1) {
      float n = __shfl_up(gv, (unsigned)off, 64);
      if (tid >= off) gv += n;
    }
    gcs[tid] = gv;   // inclusive cumsum of g within chunk
  }
  __syncthreads();

  // prefetch v for RHS (latency hides under P1 MFMA)
  const int hh = tid >> 7, cI = tid & 127;
  float vpre[32];
  if (cI < 64) {
#pragma unroll
    for (int r = 0; r < 32; r++)
      vpre[r] = (float)vs[cb + (size_t)(hh * 32 + r) * 64 + cI];
  }

  // P1: At[s][t] = (t>s)? beta_t*exp(gc_t-gc_s)*(k_t.k_s) : 0  via MFMA
  {
    bfx8_t aS[2];
#pragma unroll
    for (int kh = 0; kh < 2; kh++)
      aS[kh] = BF8(&Kb[(16 * w + (lane & 15)) * 72 + kh * 32 + (lane >> 4) * 8]);
#pragma unroll
    for (int j = 0; j < 4; j++) {
      if (j < w) {  // strictly-lower tiles: zero
#pragma unroll
        for (int r = 0; r < 4; r++)
          At[(16 * w + (lane >> 4) * 4 + r) * 68 + 16 * j + (lane & 15)] = 0.f;
      } else {
        f32x4_t acc = {0.f, 0.f, 0.f, 0.f};
#pragma unroll
        for (int kh = 0; kh < 2; kh++) {
          bfx8_t bS = BF8(&Kb[(16 * j + (lane & 15)) * 72 + kh * 32 + (lane >> 4) * 8]);
          acc = __builtin_amdgcn_mfma_f32_16x16x32_bf16(aS[kh], bS, acc, 0, 0, 0);
        }
        const int t = 16 * j + (lane & 15);
        const float bt = bcs[t], gt = gcs[t];
#pragma unroll
        for (int r = 0; r < 4; r++) {
          const int s = 16 * w + (lane >> 4) * 4 + r;
          At[s * 68 + t] = (t > s) ? bt * __expf(gt - gcs[s]) * acc[r] : 0.f;
        }
      }
    }
  }

  // P2: RHS init: X = [ beta*V | beta*exp(gc)*K ], thread = (hh, cI)
  float X[32];
  if (cI < 64) {
#pragma unroll
    for (int r = 0; r < 32; r++) X[r] = bcs[hh * 32 + r] * vpre[r];
  } else {
#pragma unroll
    for (int r = 0; r < 32; r++) {
      int s = hh * 32 + r;
      X[r] = bcs[s] * __expf(gcs[s]) * (float)Kb[s * 72 + (cI - 64)];
    }
  }

  // P3: forward substitution (fp32; At diag/lower zeros -> unpredicated ok;
  // first in-loop barrier also orders P1's At writes before the first At read)
#pragma unroll
  for (int s = 0; s < 64; ++s) {
    if (hh == (s >> 5)) xbc[s & 1][cI] = X[s & 31];
    __syncthreads();
    float xs = xbc[s & 1][cI];
    const float* atrow = &At[s * 68 + hh * 32];
#pragma unroll
    for (int j = 0; j < 8; j++) {
      float4 a4 = F4(atrow + 4 * j);
      X[4 * j + 0] = fmaf(-a4.x, xs, X[4 * j + 0]);
      X[4 * j + 1] = fmaf(-a4.y, xs, X[4 * j + 1]);
      X[4 * j + 2] = fmaf(-a4.z, xs, X[4 * j + 2]);
      X[4 * j + 3] = fmaf(-a4.w, xs, X[4 * j + 3]);
    }
  }
  __syncthreads();  // subst done; At dead, Kb reads done

  // P5: Dv/W global writes (from regs); XTb transposed bf16; KdTb over Kb
  if (cI < 64) {
#pragma unroll
    for (int r = 0; r < 32; r++)
      Dvg[(size_t)task * 4096 + (size_t)(hh * 32 + r) * 64 + cI] = X[r];
  } else {
#pragma unroll
    for (int r = 0; r < 32; r++)
      Wgb[(size_t)task * 4096 + (size_t)(hh * 32 + r) * 64 + (cI - 64)] = (__bf16)X[r];
  }
#pragma unroll
  for (int i = 0; i < 16; i++)
    *reinterpret_cast<uint32_t*>(&XTb[cI * 72 + hh * 32 + 2 * i]) = bf2pack(X[2 * i], X[2 * i + 1]);
  { // KdTb[d][s] = bf16( K[s][d] * exp(gc_63 - gc_s) )  from staged regs
    const float ek = __expf(gcs[63] - gcs[sr]);
#pragma unroll
    for (int i = 0; i < 8; i++) {
      KdTb[(sd0 + i) * 72 + sr]     = (__bf16)((float)kst0[i] * ek);
      KdTb[(sd0 + 8 + i) * 72 + sr] = (__bf16)((float)kst1[i] * ek);
    }
  }
  __syncthreads();

  // P6: M[d][e] = sum_s Kd[s][d]W[s][e]; PT[v][d] = sum_s Dv[s][v]Kd[s][d]
  {
    bfx8_t aM[2], aP[2];
#pragma unroll
    for (int kh = 0; kh < 2; kh++) {
      aM[kh] = BF8(&KdTb[(16 * w + (lane & 15)) * 72 + kh * 32 + (lane >> 4) * 8]);
      aP[kh] = BF8(&XTb [(16 * w + (lane & 15)) * 72 + kh * 32 + (lane >> 4) * 8]);
    }
#pragma unroll
    for (int j = 0; j < 4; j++) {
      f32x4_t mAcc = {0.f, 0.f, 0.f, 0.f}, pAcc = {0.f, 0.f, 0.f, 0.f};
#pragma unroll
      for (int kh = 0; kh < 2; kh++) {
        bfx8_t bW = BF8(&XTb [(64 + 16 * j + (lane & 15)) * 72 + kh * 32 + (lane >> 4) * 8]);
        bfx8_t bK = BF8(&KdTb[(16 * j + (lane & 15)) * 72 + kh * 32 + (lane >> 4) * 8]);
        mAcc = __builtin_amdgcn_mfma_f32_16x16x32_bf16(aM[kh], bW, mAcc, 0, 0, 0);
        pAcc = __builtin_amdgcn_mfma_f32_16x16x32_bf16(aP[kh], bK, pAcc, 0, 0, 0);
      }
#pragma unroll
      for (int r = 0; r < 4; r++) {
        const int drow = 16 * w + (lane >> 4) * 4 + r;  // M row d / PT row v
        const int ecol = 16 * j + (lane & 15);          // M col e / PT col d
        const int ge = ecol >> 2;
        const int ges = (ge & 8) | ((ge & 7) ^ (drow & 7));  // chunkB swizzle
        Mg [(size_t)task * 4096 + drow * 64 + ges * 4 + (ecol & 3)] = mAcc[r];
        PTg[(size_t)task * 4096 + drow * 64 + ecol] = pAcc[r];
      }
    }
  }
  if (tid == 0) egb[task] = __expf(gcs[63]);
}

// Kernel B: sequential over chunks (unchanged).
__global__ __launch_bounds__(64) void chunkB(
    const float* __restrict__ Mg, const float* __restrict__ PTg,
    const float* __restrict__ egb, float* __restrict__ hTg) {
  const int bh = blockIdx.x & 31, vq = blockIdx.x >> 5;
  const int tid = threadIdx.x;
  const int tv = tid >> 4, td = tid & 15;
  __shared__ __align__(16) float Ml[2][64 * 64];
  __shared__ __align__(16) float hT[8 * 68];

  float h[2][4];
#pragma unroll
  for (int r = 0; r < 2; r++)
#pragma unroll
    for (int c = 0; c < 4; c++) h[r][c] = 0.f;
#pragma unroll
  for (int r = 0; r < 2; r++)
#pragma unroll
    for (int c = 0; c < 4; c++) hT[(tv * 2 + r) * 68 + c * 16 + td] = 0.f;

  const char* mb = (const char*)(Mg + (size_t)bh * 32 * 4096);
#pragma unroll
  for (int j = 0; j < 16; j++)
    gload_lds16(mb + j * 1024 + tid * 16, &Ml[0][j * 256]);

  const int kk = (td & 7) << 2;
  int cur = 0;
  for (int cch = 0; cch < 32; ++cch) {
    const size_t tb = ((size_t)bh * 32 + cch) * 4096;
    asm volatile("s_waitcnt vmcnt(0)" ::: "memory");
    __builtin_amdgcn_sched_barrier(0);
    if (cch < 31) {
#pragma unroll
      for (int j = 0; j < 16; j++)
        gload_lds16(mb + (size_t)(cch + 1) * 16384 + j * 1024 + tid * 16,
                    &Ml[cur ^ 1][j * 256]);
    }
    float ptc[2][4];
#pragma unroll
    for (int r = 0; r < 2; r++)
#pragma unroll
      for (int c = 0; c < 4; c++)
        ptc[r][c] = PTg[tb + (size_t)(vq * 8 + tv * 2 + r) * 64 + c * 16 + td];
    const float egc = egb[bh * 32 + cch];
#pragma unroll
    for (int r = 0; r < 2; r++)
#pragma unroll
      for (int c = 0; c < 4; c++)
        hTg[tb + (size_t)(vq * 8 + tv * 2 + r) * 64 + c * 16 + td] = h[r][c];
    float acc[2][4] = {};
#pragma unroll
    for (int e0 = 0; e0 < 64; e0 += 4) {
      const int es = (e0 & 32) | ((e0 & 28) ^ kk);
      float4 h4[2], m4[4];
#pragma unroll
      for (int r = 0; r < 2; r++) h4[r] = F4(&hT[(tv * 2 + r) * 68 + e0]);
#pragma unroll
      for (int c = 0; c < 4; c++) m4[c] = F4(&Ml[cur][(c * 16 + td) * 64 + es]);
#pragma unroll
      for (int r = 0; r < 2; r++)
#pragma unroll
        for (int c = 0; c < 4; c++) {
          acc[r][c] = fmaf(h4[r].x, m4[c].x, acc[r][c]);
          acc[r][c] = fmaf(h4[r].y, m4[c].y, acc[r][c]);
          acc[r][c] = fmaf(h4[r].z, m4[c].z, acc[r][c]);
          acc[r][c] = fmaf(h4[r].w, m4[c].w, acc[r][c]);
        }
    }
#pragma unroll
    for (int r = 0; r < 2; r++)
#pragma unroll
      for (int c = 0; c < 4; c++)
        h[r][c] = egc * h[r][c] - acc[r][c] + ptc[r][c];
#pragma unroll
    for (int r = 0; r < 2; r++)
#pragma unroll
      for (int c = 0; c < 4; c++) hT[(tv * 2 + r) * 68 + c * 16 + td] = h[r][c];
    cur ^= 1;
  }
}

// Kernel C: O = diag(exp(gc)) Q h0 + Sm * (Dv - W h0), all products via MFMA.
__global__ __launch_bounds__(256, 3) void chunkC(
    const __bf16* __restrict__ qs, const __bf16* __restrict__ ks_,
    const float* __restrict__ gbuf, const float* __restrict__ Dvg,
    const __bf16* __restrict__ Wgb, const float* __restrict__ hTg,
    float* __restrict__ o_raw) {
  const int task = blockIdx.x, bh = task >> 5, cc = task & 31;
  const int b = bh >> 4, hd = bh & 15;
  const int tid = threadIdx.x;
  const int w = tid >> 6, lane = tid & 63;
  __shared__ __align__(16) __bf16 cQb[64 * 72];  // Q rows
  __shared__ __align__(16) char  regK[9216];     // cKb [s][d] -> dTb [v][s]
  __shared__ __align__(16) __bf16 cWb[64 * 72];  // W rows
  __shared__ __align__(16) __bf16 hTb[64 * 72];  // hT rows (v-major)
  __shared__ __align__(16) __bf16 Smb[64 * 72];  // gated scores [t][s]
  __shared__ float gcs[64];
  __bf16* cKb = (__bf16*)regK;
  __bf16* dTb = (__bf16*)regK;

  const size_t cb = ((size_t)bh * 2048 + cc * 64) * 64;
  // stage Q, K (bf16 copies), hT (fp32->bf16), W (bf16 copy), cumsum g
  { int s = tid >> 2, d0 = (tid & 3) * 16;
    BF8W(&cQb[s * 72 + d0])     = BF8(&qs [cb + (size_t)s * 64 + d0]);
    BF8W(&cQb[s * 72 + d0 + 8]) = BF8(&qs [cb + (size_t)s * 64 + d0 + 8]);
    BF8W(&cKb[s * 72 + d0])     = BF8(&ks_[cb + (size_t)s * 64 + d0]);
    BF8W(&cKb[s * 72 + d0 + 8]) = BF8(&ks_[cb + (size_t)s * 64 + d0 + 8]);
#pragma unroll
    for (int i = 0; i < 4; i++)
      *reinterpret_cast<bfx4_t*>(&hTb[s * 72 + d0 + 4 * i]) =
          to_bf4(F4(&hTg[(size_t)task * 4096 + (size_t)s * 64 + d0 + 4 * i]));
    BF8W(&cWb[s * 72 + d0])     = BF8(&Wgb[(size_t)task * 4096 + (size_t)s * 64 + d0]);
    BF8W(&cWb[s * 72 + d0 + 8]) = BF8(&Wgb[(size_t)task * 4096 + (size_t)s * 64 + d0 + 8]);
  }
  if (tid < 64) {
    float gv = gbuf[(size_t)bh * 2048 + cc * 64 + tid];
#pragma unroll
    for (int off = 1; off < 64; off <<= 1) {
      float n = __shfl_up(gv, (unsigned)off, 64);
      if (tid >= off) gv += n;
    }
    gcs[tid] = gv;
  }
  __syncthreads();

  // P1: S = QK^T (gate -> Smb bf16) and QH = Q hT^T (regs), wave w owns t-tile w
  f32x4_t qh[4];
  {
    bfx8_t aQ[2];
#pragma unroll
    for (int kh = 0; kh < 2; kh++)
      aQ[kh] = BF8(&cQb[(16 * w + (lane & 15)) * 72 + kh * 32 + (lane >> 4) * 8]);
#pragma unroll
    for (int j = 0; j < 4; j++) {
      f32x4_t sAcc = {0.f, 0.f, 0.f, 0.f};
      qh[j] = f32x4_t{0.f, 0.f, 0.f, 0.f};
#pragma unroll
      for (int kh = 0; kh < 2; kh++) {
        bfx8_t bK = BF8(&cKb[(16 * j + (lane & 15)) * 72 + kh * 32 + (lane >> 4) * 8]);
        bfx8_t bH = BF8(&hTb[(16 * j + (lane & 15)) * 72 + kh * 32 + (lane >> 4) * 8]);
        sAcc = __builtin_amdgcn_mfma_f32_16x16x32_bf16(aQ[kh], bK, sAcc, 0, 0, 0);
        qh[j] = __builtin_amdgcn_mfma_f32_16x16x32_bf16(aQ[kh], bH, qh[j], 0, 0, 0);
      }
      const int s = 16 * j + (lane & 15);
      const float gs = gcs[s];
#pragma unroll
      for (int r = 0; r < 4; r++) {
        const int t = 16 * w + (lane >> 4) * 4 + r;
        float sv = (s <= t) ? __expf(gcs[t] - gs) * sAcc[r] : 0.f;
        Smb[t * 72 + s] = (__bf16)sv;
      }
    }
  }
  __syncthreads();  // Smb visible; cKb reads done

  // P3: U = W hT^T; delta = Dv - U -> dTb[v][s] bf16 (over cKb region)
  {
    bfx8_t aW[2];
#pragma unroll
    for (int kh = 0; kh < 2; kh++)
      aW[kh] = BF8(&cWb[(16 * w + (lane & 15)) * 72 + kh * 32 + (lane >> 4) * 8]);
#pragma unroll
    for (int j = 0; j < 4; j++) {
      f32x4_t u = {0.f, 0.f, 0.f, 0.f};
#pragma unroll
      for (int kh = 0; kh < 2; kh++) {
        bfx8_t bH = BF8(&hTb[(16 * j + (lane & 15)) * 72 + kh * 32 + (lane >> 4) * 8]);
        u = __builtin_amdgcn_mfma_f32_16x16x32_bf16(aW[kh], bH, u, 0, 0, 0);
      }
      const int v = 16 * j + (lane & 15);
#pragma unroll
      for (int r = 0; r < 4; r++) {
        const int s = 16 * w + (lane >> 4) * 4 + r;
        float dl = Dvg[(size_t)task * 4096 + (size_t)s * 64 + v] - u[r];
        dTb[v * 72 + s] = (__bf16)dl;
      }
    }
  }
  __syncthreads();

  // P4: O = exp(gc_t)*QH + Sm*delta; write o_raw
  {
    bfx8_t aS2[2];
#pragma unroll
    for (int kh = 0; kh < 2; kh++)
      aS2[kh] = BF8(&Smb[(16 * w + (lane & 15)) * 72 + kh * 32 + (lane >> 4) * 8]);
    float esc[4];
#pragma unroll
    for (int r = 0; r < 4; r++) esc[r] = __expf(gcs[16 * w + (lane >> 4) * 4 + r]);
#pragma unroll
    for (int j = 0; j < 4; j++) {
#pragma unroll
      for (int r = 0; r < 4; r++) qh[j][r] *= esc[r];
#pragma unroll
      for (int kh = 0; kh < 2; kh++) {
        bfx8_t bD = BF8(&dTb[(16 * j + (lane & 15)) * 72 + kh * 32 + (lane >> 4) * 8]);
        qh[j] = __builtin_amdgcn_mfma_f32_16x16x32_bf16(aS2[kh], bD, qh[j], 0, 0, 0);
      }
      const int v = 16 * j + (lane & 15);
#pragma unroll
      for (int r = 0; r < 4; r++) {
        const int t = 16 * w + (lane >> 4) * 4 + r;
        o_raw[(((size_t)b * 2048 + cc * 64 + t) * 16 + hd) * 64 + v] = qh[j][r];
      }
    }
  }
}

// ---------------- gate * silu + per-head RMS norm -> bf16 (Y bf16) ----------------
__global__ __launch_bounds__(256) void gate_rms(
    const float* __restrict__ o_raw, const __bf16* __restrict__ Y,
    const float* __restrict__ rms_w, __bf16* __restrict__ o2b) {
  const int blk = blockIdx.x;
  const int tid = threadIdx.x;
  const int H = tid >> 4, d0 = (tid & 15) * 4;
  const size_t ob = (size_t)blk * 1024 + H * 64 + d0;
  float4 o = *reinterpret_cast<const float4*>(o_raw + ob);
  bfx4_t gb = *reinterpret_cast<const bfx4_t*>(Y + (size_t)blk * NPAD + 3104 + H * 64 + d0);
  float o2[4];
  o2[0] = o.x * siluf((float)gb[0]); o2[1] = o.y * siluf((float)gb[1]);
  o2[2] = o.z * siluf((float)gb[2]); o2[3] = o.w * siluf((float)gb[3]);
  float ssq = o2[0] * o2[0] + o2[1] * o2[1] + o2[2] * o2[2] + o2[3] * o2[3];
  ssq += __shfl_xor(ssq, 1, 64);
  ssq += __shfl_xor(ssq, 2, 64);
  ssq += __shfl_xor(ssq, 4, 64);
  ssq += __shfl_xor(ssq, 8, 64);
  const float scale = rsqrtf(ssq * (1.f / 64.f) + 1e-5f);
  bfx4_t r;
#pragma unroll
  for (int i = 0; i < 4; i++) r[i] = (__bf16)(o2[i] * scale * rms_w[d0 + i]);
  *reinterpret_cast<bfx4_t*>(o2b + ob) = r;
}

// ---------------- launch ----------------
extern "C" void kernel_launch(void* const* d_in, const int* in_sizes, int n_in,
                              void* d_out, int out_size, void* d_ws, size_t ws_size,
                              hipStream_t stream) {
  (void)in_sizes; (void)n_in; (void)out_size; (void)ws_size;
  const float* hidden = (const float*)d_in[0];
  const float* w_qkv  = (const float*)d_in[1];
  const float* w_ab   = (const float*)d_in[2];
  const float* w_conv = (const float*)d_in[3];
  const float* A_log  = (const float*)d_in[4];
  const float* dt_b   = (const float*)d_in[5];
  const float* rms_w  = (const float*)d_in[6];
  const float* w_o    = (const float*)d_in[7];
  float* out = (float*)d_out;

  char* ws = (char*)d_ws;
  size_t off = 0;
  auto alloc = [&](size_t bytes) { void* p = ws + off; off += (bytes + 255) & ~(size_t)255; return p; };
  __bf16* Xb   = (__bf16*)alloc((size_t)4096 * 1024 * 2);   // dead after gemm1
  __bf16* Wb   = (__bf16*)alloc((size_t)NPAD * 1024 * 2);   // dead after gemm1
  __bf16* Wob  = (__bf16*)alloc((size_t)1024 * 1024 * 2);
  __bf16* Y    = (__bf16*)alloc((size_t)4096 * NPAD * 2);   // bf16 Y
  __bf16* qs   = (__bf16*)alloc((size_t)32 * 2048 * 64 * 2);
  __bf16* ks   = (__bf16*)alloc((size_t)32 * 2048 * 64 * 2);
  __bf16* vs   = (__bf16*)alloc((size_t)32 * 2048 * 64 * 2);
  float* gbuf  = (float*)alloc((size_t)32 * 2048 * 4);
  float* bbuf  = (float*)alloc((size_t)32 * 2048 * 4);
  float* Dvg   = (float*)alloc((size_t)1024 * 4096 * 4);
  __bf16* Wgb  = (__bf16*)alloc((size_t)1024 * 4096 * 2);
  float* Mg    = (float*)alloc((size_t)1024 * 4096 * 4);
  float* PTg   = (float*)alloc((size_t)1024 * 4096 * 4);
  float* hTg   = (float*)alloc((size_t)1024 * 4096 * 4);
  float* egb   = (float*)alloc((size_t)1024 * 4);
  __bf16* o2b  = (__bf16*)alloc((size_t)4096 * 1024 * 2);
  // o_raw (16MB) aliases Xb+Wb (16.6MB): Xb/Wb dead after gemm1
  float* o_raw = (float*)Xb;

  cvt_f32_bf16<<<4096, 256, 0, stream>>>(hidden, Xb);
  cvt_weights<<<4224, 256, 0, stream>>>(w_qkv, w_ab, Wb);
  cvt_f32_bf16<<<1024, 256, 0, stream>>>(w_o, Wob);
  gemm_bt_b16<<<32 * 33, 256, 0, stream>>>(Xb, Wb, Y, 1024, 1024, 1024, NPAD);
  prep_kernel<<<4096, 384, 0, stream>>>(Y, w_conv, A_log, dt_b, qs, ks, vs, gbuf, bbuf);
  chunkA<<<1024, 256, 0, stream>>>(ks, vs, gbuf, bbuf, Dvg, Wgb, Mg, PTg, egb);
  chunkB<<<256, 64, 0, stream>>>(Mg, PTg, egb, hTg);
  chunkC<<<1024, 256, 0, stream>>>(qs, ks, gbuf, Dvg, Wgb, hTg, o_raw);
  gate_rms<<<4096, 256, 0, stream>>>(o_raw, Y, rms_w, o2b);
  gemm_bt<<<32 * 8, 256, 0, stream>>>(o2b, Wob, out, 1024, 1024, 1024, 1024);
}